// Round 14
// baseline (875.475 us; speedup 1.0000x reference)
//
#include <hip/hip_runtime.h>
#include <hip/hip_fp16.h>
#include <math.h>

#define TOK  1024
#define DIMK 4096
#define HID  11008

typedef long long ll;
typedef int v4i  __attribute__((ext_vector_type(4)));
typedef int v16i __attribute__((ext_vector_type(16)));

// ---------- ws layout ----------
#define T13_OFF 0ull
#define LUT_OFF 11272192ull
#define CS1_OFF (LUT_OFF + 32768ull)
#define CS3_OFF (CS1_OFF + 44032ull)
#define XQ_OFF  (CS3_OFF + 44032ull)
#define WQ_OFF  (XQ_OFF + 4194304ull)
#define PLANE   45088768ull                          // 11008*4096 bytes
#define WS_NEED (WQ_OFF + 6ull * PLANE)              // ~273 MB

// ---------- exact fp16-silu requant (proven in round 2) ----------
__device__ __forceinline__ int gate_requant(int g) {
  const float vf = __half2float(__float2half((float)g * (1.0f / 65536.0f)));
  const float e32 = (float)exp(-(double)vf);
  const float e16 = __half2float(__float2half(e32));
  const float d16 = __half2float(__float2half(1.0f + e16));
  const float s16 = __half2float(__float2half(1.0f / d16));
  const float p16 = __half2float(__float2half(vf * s16));
  return __float2int_rn(p16 * 65536.0f);
}

__device__ __forceinline__ v16i vzero16() {
  v16i z;
  #pragma unroll
  for (int i = 0; i < 16; ++i) z[i] = 0;
  return z;
}

// async global->LDS, 16B per lane; lds ptr must be wave-uniform
__device__ __forceinline__ void gll(const void* g, void* l) {
  __builtin_amdgcn_global_load_lds((const __attribute__((address_space(1))) unsigned int*)g,
                                   (__attribute__((address_space(3))) unsigned int*)l,
                                   16, 0, 0);
}

// ============================================================
// Pre-pass kernels (r12-proven)
// ============================================================

__global__ void lut_kernel(int* __restrict__ lut) {
  const int i = blockIdx.x * blockDim.x + threadIdx.x;   // 0..8191
  lut[i] = gate_requant(i - 4096);
}

// xq = (i8)(x - 128), packed bytes
__global__ __launch_bounds__(256)
void xq_kernel(const int* __restrict__ x, char* __restrict__ xq) {
  const size_t base = ((size_t)blockIdx.x * 256 + threadIdx.x) * 16;
  int w[4];
  #pragma unroll
  for (int i = 0; i < 4; ++i) {
    const int4 v = *reinterpret_cast<const int4*>(&x[base + i * 4]);
    w[i] = ((v.x & 255) | ((v.y & 255) << 8) | ((v.z & 255) << 16) | ((v.w & 255) << 24)) ^ 0x80808080;
  }
  *reinterpret_cast<int4*>(&xq[base]) = make_int4(w[0], w[1], w[2], w[3]);
}

// All three weight matrices in one dispatch (r12 version, vectorized stores).
__global__ __launch_bounds__(256)
void prequant_all(const float* __restrict__ w1, const float* __restrict__ w3,
                  const float* __restrict__ w2, char* __restrict__ wq,
                  int* __restrict__ cs1, int* __restrict__ cs3)
{
  const int bid = blockIdx.x;
  const int m = bid / 11008;            // 0,1,2 (uniform per block)
  const int rb = bid - m * 11008;
  const float* src = (m == 0) ? w1 : ((m == 1) ? w3 : w2);
  int4* lo = (int4*)(wq + (size_t)(2 * m) * PLANE);
  int4* hi = (int4*)(wq + (size_t)(2 * m + 1) * PLANE);
  const int t = threadIdx.x;
  const size_t fbase = (size_t)rb * 4096 + (size_t)t * 16;

  int sum = 0;
  int lob[4], hib[4];
  #pragma unroll
  for (int i = 0; i < 4; ++i) {
    const float4 f = *reinterpret_cast<const float4*>(&src[fbase + i * 4]);
    const int q0 = __float2int_rn(f.x * 65536.0f);
    const int q1 = __float2int_rn(f.y * 65536.0f);
    const int q2 = __float2int_rn(f.z * 65536.0f);
    const int q3 = __float2int_rn(f.w * 65536.0f);
    sum += q0 + q1 + q2 + q3;
    lob[i] = (q0 & 127) | ((q1 & 127) << 8) | ((q2 & 127) << 16) | ((q3 & 127) << 24);
    hib[i] = ((q0 >> 7) & 255) | (((q1 >> 7) & 255) << 8) |
             (((q2 >> 7) & 255) << 16) | (((q3 >> 7) & 255) << 24);
  }
  const size_t o = (size_t)rb * 256 + t;
  lo[o] = make_int4(lob[0], lob[1], lob[2], lob[3]);
  hi[o] = make_int4(hib[0], hib[1], hib[2], hib[3]);
  if (m < 2) {
    #pragma unroll
    for (int off = 32; off > 0; off >>= 1) sum += __shfl_xor(sum, off, 64);
    if ((t & 63) == 0) atomicAdd(((m == 0) ? cs1 : cs3) + rb, sum);
  }
}

// ============================================================
// Up GEMM: ZERO-BARRIER wave-private pipelines.
// BT=256, BN=64, 4 planes, BK=32; 512 thr = 8 waves, fully independent.
// Wave (rf=w&3, cf=w>>2): rows rf*64..+64, cols cf*32..+32, all 4 planes.
// Each wave stages its OWN 6KB tile (2 A + 4 B segs of 1KB) into PRIVATE
// LDS via global_load_lds, double-buffered (12KB/wave, 96KB/block), and
// syncs only via its own vmcnt/lgkmcnt. No s_barrier in the loop: waves
// drift freely, so one wave's MFMAs cover another's LDS/load latency.
// vmcnt(6): the 6 glls for tile kt+1 stay in flight across tile kt's MFMAs.
// B panels shared by 4 waves / 8 row-blocks hit L2 (XCD swizzle 688=8*86).
// ============================================================

__global__ __launch_bounds__(512, 1)
void up_gemm(const char* __restrict__ xq, const char* __restrict__ wq,
             const int* __restrict__ csum1, const int* __restrict__ csum3,
             const int* __restrict__ lut, char* __restrict__ t13)
{
  __shared__ char smem[98304];          // 8 waves x 2 bufs x 6KB
  const int tid = threadIdx.x;
  const int w = tid >> 6, l = tid & 63;
  const int rf = w & 3, cf = w >> 2;
  const int l16 = l * 16;

  // bijective XCD swizzle: 688 = 8 * 86
  const int flat = blockIdx.x;
  const int g = (flat & 7) * 86 + (flat >> 3);
  const int col0 = (g >> 2) * 64;
  const int row0 = (g & 3) * 256;

  // global fragment pointers (per wave), k advances by 32 per tile
  const char* pa0 = xq + (size_t)(row0 + rf * 64 +  0 + (l & 31)) * DIMK + (l >> 5) * 16;
  const char* pa1 = xq + (size_t)(row0 + rf * 64 + 32 + (l & 31)) * DIMK + (l >> 5) * 16;
  const size_t offB = (size_t)(col0 + cf * 32 + (l & 31)) * DIMK + (l >> 5) * 16;
  const char* pb0 = wq + 0ull * PLANE + offB;
  const char* pb1 = wq + 1ull * PLANE + offB;
  const char* pb2 = wq + 2ull * PLANE + offB;
  const char* pb3 = wq + 3ull * PLANE + offB;

  // wave-private LDS: buf0 at w*12288, buf1 at w*12288+6144; segs 1KB each
  char* base0 = smem + w * 12288;
  char* base1 = base0 + 6144;

  v16i acc[2][4];
  #pragma unroll
  for (int m = 0; m < 2; ++m)
    #pragma unroll
    for (int p = 0; p < 4; ++p) acc[m][p] = vzero16();

  #define UP_STAGE(bp, kb) { \
    gll(pa0 + (kb), (bp) + 0);    gll(pa1 + (kb), (bp) + 1024); \
    gll(pb0 + (kb), (bp) + 2048); gll(pb1 + (kb), (bp) + 3072); \
    gll(pb2 + (kb), (bp) + 4096); gll(pb3 + (kb), (bp) + 5120); }

  #define UP_COMPUTE(bp) { \
    const v4i av0 = *(const v4i*)((bp) + 0    + l16); \
    const v4i av1 = *(const v4i*)((bp) + 1024 + l16); \
    const v4i b0  = *(const v4i*)((bp) + 2048 + l16); \
    const v4i b1  = *(const v4i*)((bp) + 3072 + l16); \
    const v4i b2  = *(const v4i*)((bp) + 4096 + l16); \
    const v4i b3  = *(const v4i*)((bp) + 5120 + l16); \
    asm volatile("s_waitcnt lgkmcnt(0)" ::: "memory"); \
    __builtin_amdgcn_sched_barrier(0); \
    acc[0][0] = __builtin_amdgcn_mfma_i32_32x32x32_i8(av0, b0, acc[0][0], 0, 0, 0); \
    acc[0][1] = __builtin_amdgcn_mfma_i32_32x32x32_i8(av0, b1, acc[0][1], 0, 0, 0); \
    acc[0][2] = __builtin_amdgcn_mfma_i32_32x32x32_i8(av0, b2, acc[0][2], 0, 0, 0); \
    acc[0][3] = __builtin_amdgcn_mfma_i32_32x32x32_i8(av0, b3, acc[0][3], 0, 0, 0); \
    acc[1][0] = __builtin_amdgcn_mfma_i32_32x32x32_i8(av1, b0, acc[1][0], 0, 0, 0); \
    acc[1][1] = __builtin_amdgcn_mfma_i32_32x32x32_i8(av1, b1, acc[1][1], 0, 0, 0); \
    acc[1][2] = __builtin_amdgcn_mfma_i32_32x32x32_i8(av1, b2, acc[1][2], 0, 0, 0); \
    acc[1][3] = __builtin_amdgcn_mfma_i32_32x32x32_i8(av1, b3, acc[1][3], 0, 0, 0); }

  const int NT = DIMK / 32;   // 128 tiles (even)
  UP_STAGE(base0, 0)
  #pragma unroll 1
  for (int kt = 0; kt < NT; kt += 2) {
    // even tile kt (buf0); stage kt+1 into buf1 first, keep it in flight
    UP_STAGE(base1, (kt + 1) * 32)
    asm volatile("s_waitcnt vmcnt(6)" ::: "memory");   // tile kt landed
    UP_COMPUTE(base0)
    // odd tile kt+1 (buf1); stage kt+2 into buf0
    if (kt + 2 < NT) {
      UP_STAGE(base0, (kt + 2) * 32)
      asm volatile("s_waitcnt vmcnt(6)" ::: "memory"); // tile kt+1 landed
    } else {
      asm volatile("s_waitcnt vmcnt(0)" ::: "memory");
    }
    UP_COMPUTE(base1)
  }
  #undef UP_STAGE
  #undef UP_COMPUTE

  const int col = col0 + cf * 32 + (l & 31);
  const int cs1v = csum1[col], cs3v = csum3[col];
  #pragma unroll
  for (int m = 0; m < 2; ++m) {
    #pragma unroll
    for (int r = 0; r < 16; ++r) {
      const int row = row0 + rf * 64 + m * 32 + (r & 3) + 8 * (r >> 2) + 4 * (l >> 5);
      const ll t1 = (ll)acc[m][0][r] + (((ll)acc[m][1][r] + cs1v) << 7);
      int gg = (int)((t1 + 32768) >> 16);
      gg = gg < -4096 ? -4096 : (gg > 4095 ? 4095 : gg);
      const ll t3 = (ll)acc[m][2][r] + (((ll)acc[m][3][r] + cs3v) << 7);
      const int q3 = (int)((t3 + 32768) >> 16);
      const int gate = lut[gg + 4096];
      t13[(size_t)row * HID + col] = (char)((int)(((ll)gate * q3 + 32768) >> 16));
    }
  }
}

// ============================================================
// Down GEMM (round-7 proven): BT=256, BN=64, 2 planes, BK=64 over HID;
// 512 thr = 8 waves, triple buffer 3x24KB, grid 256 = 1/CU.
// ============================================================
#define DN_BUF 24576

__global__ __launch_bounds__(512, 1)
void down_gemm(const char* __restrict__ t13, const char* __restrict__ w2lo,
               const char* __restrict__ w2hi, int* __restrict__ out)
{
  __shared__ char smem[3 * DN_BUF];
  const int tid = threadIdx.x;
  const int w = tid >> 6, l = tid & 63;
  const int rf = w & 3, cf = w >> 2;
  const int l16 = l * 16;

  // bijective XCD swizzle: 256 = 8 * 32
  const int flat = blockIdx.x;
  const int g = (flat & 7) * 32 + (flat >> 3);
  const int col0 = (g >> 2) * 64;
  const int row0 = (g & 3) * 256;

  const char* gA = t13 + (size_t)(row0 + w * 32 + (l & 31)) * HID + (l >> 5) * 16;
  const char* pB = (w >> 2) ? w2hi : w2lo;
  const char* gB = pB + (size_t)(col0 + ((w >> 1) & 1) * 32 + (l & 31)) * HID
                 + (w & 1) * 32 + (l >> 5) * 16;
  const unsigned dA0 = (2 * w + 0) * 1024, dA1 = (2 * w + 1) * 1024;
  const unsigned dB = 16384 + w * 1024;

  v16i acc[2][2];
  #pragma unroll
  for (int m = 0; m < 2; ++m)
    #pragma unroll
    for (int p = 0; p < 2; ++p) acc[m][p] = vzero16();

  // prologue: tiles 0,1 (3 gll each); wait tile 0
  gll(gA, smem + dA0);  gll(gA + 32, smem + dA1);  gll(gB, smem + dB);
  gll(gA + 64, smem + DN_BUF + dA0);  gll(gA + 96, smem + DN_BUF + dA1);
  gll(gB + 64, smem + DN_BUF + dB);
  asm volatile("s_waitcnt vmcnt(3)" ::: "memory");
  __builtin_amdgcn_s_barrier();

  const int NT = HID / 64;   // 172
  unsigned co = 0, so = 2 * DN_BUF;
  for (int kt = 0; kt < NT; ++kt) {
    const char* sb = smem + co;
    const bool st = (kt + 2 < NT);
    const int kb = (kt + 2) * 64;
    // ---------------- phase 0 (ks = 0) ----------------
    {
      const v4i av0 = *(const v4i*)(sb + (rf * 4 + 0) * 1024 + l16);
      const v4i av1 = *(const v4i*)(sb + (rf * 4 + 2) * 1024 + l16);
      const v4i bL  = *(const v4i*)(sb + 16384 + (0 * 4 + cf * 2) * 1024 + l16);
      const v4i bH  = *(const v4i*)(sb + 16384 + (1 * 4 + cf * 2) * 1024 + l16);
      if (st) { gll(gA + kb, smem + so + dA0); gll(gA + kb + 32, smem + so + dA1); }
      __builtin_amdgcn_s_barrier();
      asm volatile("s_waitcnt lgkmcnt(0)" ::: "memory");
      __builtin_amdgcn_sched_barrier(0);
      __builtin_amdgcn_s_setprio(1);
      acc[0][0] = __builtin_amdgcn_mfma_i32_32x32x32_i8(av0, bL, acc[0][0], 0, 0, 0);
      acc[0][1] = __builtin_amdgcn_mfma_i32_32x32x32_i8(av0, bH, acc[0][1], 0, 0, 0);
      acc[1][0] = __builtin_amdgcn_mfma_i32_32x32x32_i8(av1, bL, acc[1][0], 0, 0, 0);
      acc[1][1] = __builtin_amdgcn_mfma_i32_32x32x32_i8(av1, bH, acc[1][1], 0, 0, 0);
      __builtin_amdgcn_s_setprio(0);
      __builtin_amdgcn_s_barrier();
    }
    // ---------------- phase 1 (ks = 1) ----------------
    {
      const v4i av0 = *(const v4i*)(sb + (rf * 4 + 1) * 1024 + l16);
      const v4i av1 = *(const v4i*)(sb + (rf * 4 + 3) * 1024 + l16);
      const v4i bL  = *(const v4i*)(sb + 16384 + (0 * 4 + cf * 2 + 1) * 1024 + l16);
      const v4i bH  = *(const v4i*)(sb + 16384 + (1 * 4 + cf * 2 + 1) * 1024 + l16);
      if (st) { gll(gB + kb, smem + so + dB); }
      __builtin_amdgcn_s_barrier();
      asm volatile("s_waitcnt lgkmcnt(0)" ::: "memory");
      __builtin_amdgcn_sched_barrier(0);
      __builtin_amdgcn_s_setprio(1);
      acc[0][0] = __builtin_amdgcn_mfma_i32_32x32x32_i8(av0, bL, acc[0][0], 0, 0, 0);
      acc[0][1] = __builtin_amdgcn_mfma_i32_32x32x32_i8(av0, bH, acc[0][1], 0, 0, 0);
      acc[1][0] = __builtin_amdgcn_mfma_i32_32x32x32_i8(av1, bL, acc[1][0], 0, 0, 0);
      acc[1][1] = __builtin_amdgcn_mfma_i32_32x32x32_i8(av1, bH, acc[1][1], 0, 0, 0);
      __builtin_amdgcn_s_setprio(0);
      if (st) { asm volatile("s_waitcnt vmcnt(3)" ::: "memory"); }
      else    { asm volatile("s_waitcnt vmcnt(0)" ::: "memory"); }
      __builtin_amdgcn_s_barrier();
    }
    if (st) so = (so == 2 * DN_BUF) ? 0 : so + DN_BUF;
    co = (co == 2 * DN_BUF) ? 0 : co + DN_BUF;
  }

  const int col = col0 + cf * 32 + (l & 31);
  #pragma unroll
  for (int m = 0; m < 2; ++m) {
    #pragma unroll
    for (int r = 0; r < 16; ++r) {
      const int row = row0 + rf * 64 + m * 32 + (r & 3) + 8 * (r >> 2) + 4 * (l >> 5);
      out[(size_t)row * DIMK + col] =
          (int)((((ll)acc[m][0][r] + ((ll)acc[m][1][r] << 7)) + 32768) >> 16);
    }
  }
}

// ============================================================
// Fallback (round-2 passing VALU kernels, used if ws too small)
// ============================================================
#define BT 64
#define BN 64
#define BK 64
#define LDST 68

__device__ __forceinline__ int mad24(int a, int b, int c) {
  return ((a << 8) >> 8) * ((b << 8) >> 8) + c;
}

__global__ __launch_bounds__(256)
void ffn_up_f(const int* __restrict__ x, const float* __restrict__ w1,
              const float* __restrict__ w3, short* __restrict__ t13)
{
  __shared__ int As[BT][LDST];
  __shared__ int B1[BK][LDST];
  __shared__ int B3[BK][LDST];
  const int tx = threadIdx.x, ty = threadIdx.y;
  const int tid = ty * 16 + tx;
  const int col0 = blockIdx.x * BN;
  const int row0 = blockIdx.y * BT;
  const int lr = tid >> 4;
  const int lk = (tid & 15) << 2;
  int acc1[16] = {0};
  int acc3[16] = {0};
  for (int k0 = 0; k0 < DIMK; k0 += BK) {
    #pragma unroll
    for (int m = 0; m < 4; ++m) {
      const int r = lr + m * 16;
      *reinterpret_cast<int4*>(&As[r][lk]) =
          *reinterpret_cast<const int4*>(&x[(size_t)(row0 + r) * DIMK + k0 + lk]);
      const float4 f1 = *reinterpret_cast<const float4*>(&w1[(size_t)(col0 + r) * DIMK + k0 + lk]);
      const float4 f3 = *reinterpret_cast<const float4*>(&w3[(size_t)(col0 + r) * DIMK + k0 + lk]);
      B1[lk + 0][r] = __float2int_rn(f1.x * 65536.0f);
      B1[lk + 1][r] = __float2int_rn(f1.y * 65536.0f);
      B1[lk + 2][r] = __float2int_rn(f1.z * 65536.0f);
      B1[lk + 3][r] = __float2int_rn(f1.w * 65536.0f);
      B3[lk + 0][r] = __float2int_rn(f3.x * 65536.0f);
      B3[lk + 1][r] = __float2int_rn(f3.y * 65536.0f);
      B3[lk + 2][r] = __float2int_rn(f3.z * 65536.0f);
      B3[lk + 3][r] = __float2int_rn(f3.w * 65536.0f);
    }
    __syncthreads();
    #pragma unroll 8
    for (int kk = 0; kk < BK; ++kk) {
      const int4 b1 = *reinterpret_cast<const int4*>(&B1[kk][tx << 2]);
      const int4 b3 = *reinterpret_cast<const int4*>(&B3[kk][tx << 2]);
      #pragma unroll
      for (int i = 0; i < 4; ++i) {
        const int av = As[(ty << 2) + i][kk] & 255;
        acc1[i*4+0] = mad24(av, b1.x, acc1[i*4+0]);
        acc1[i*4+1] = mad24(av, b1.y, acc1[i*4+1]);
        acc1[i*4+2] = mad24(av, b1.z, acc1[i*4+2]);
        acc1[i*4+3] = mad24(av, b1.w, acc1[i*4+3]);
        acc3[i*4+0] = mad24(av, b3.x, acc3[i*4+0]);
        acc3[i*4+1] = mad24(av, b3.y, acc3[i*4+1]);
        acc3[i*4+2] = mad24(av, b3.z, acc3[i*4+2]);
        acc3[i*4+3] = mad24(av, b3.w, acc3[i*4+3]);
      }
    }
    __syncthreads();
  }
  #pragma unroll
  for (int i = 0; i < 4; ++i) {
    #pragma unroll
    for (int j = 0; j < 4; ++j) {
      const int g    = (acc1[i*4+j] + 32768) >> 16;
      const int q3   = (acc3[i*4+j] + 32768) >> 16;
      const int gate = gate_requant(g);
      const int tv = (int)(((ll)gate * (ll)q3 + 32768) >> 16);
      t13[(size_t)(row0 + (ty<<2) + i) * HID + col0 + (tx<<2) + j] = (short)tv;
    }
  }
}

__global__ __launch_bounds__(256)
void ffn_down_f(const short* __restrict__ t13, const float* __restrict__ w2,
                int* __restrict__ out)
{
  __shared__ int As[BT][LDST];
  __shared__ int Bs[BK][LDST];
  const int tx = threadIdx.x, ty = threadIdx.y;
  const int tid = ty * 16 + tx;
  const int col0 = blockIdx.x * BN;
  const int row0 = blockIdx.y * BT;
  const int lr = tid >> 4;
  const int lk = (tid & 15) << 2;
  const int ar = tid >> 3;
  const int ak = (tid & 7) << 3;
  int acc[16] = {0};
  for (int k0 = 0; k0 < HID; k0 += BK) {
    #pragma unroll
    for (int m = 0; m < 2; ++m) {
      const int r = ar + m * 32;
      const int4 v = *reinterpret_cast<const int4*>(&t13[(size_t)(row0 + r) * HID + k0 + ak]);
      As[r][ak+0] = (v.x << 16) >> 16;  As[r][ak+1] = v.x >> 16;
      As[r][ak+2] = (v.y << 16) >> 16;  As[r][ak+3] = v.y >> 16;
      As[r][ak+4] = (v.z << 16) >> 16;  As[r][ak+5] = v.z >> 16;
      As[r][ak+6] = (v.w << 16) >> 16;  As[r][ak+7] = v.w >> 16;
    }
    #pragma unroll
    for (int m = 0; m < 4; ++m) {
      const int r = lr + m * 16;
      const float4 f = *reinterpret_cast<const float4*>(&w2[(size_t)(col0 + r) * HID + k0 + lk]);
      Bs[lk + 0][r] = __float2int_rn(f.x * 65536.0f);
      Bs[lk + 1][r] = __float2int_rn(f.y * 65536.0f);
      Bs[lk + 2][r] = __float2int_rn(f.z * 65536.0f);
      Bs[lk + 3][r] = __float2int_rn(f.w * 65536.0f);
    }
    __syncthreads();
    #pragma unroll 8
    for (int kk = 0; kk < BK; ++kk) {
      const int4 b = *reinterpret_cast<const int4*>(&Bs[kk][tx << 2]);
      #pragma unroll
      for (int i = 0; i < 4; ++i) {
        const int av = As[(ty << 2) + i][kk];
        acc[i*4+0] = mad24(av, b.x, acc[i*4+0]);
        acc[i*4+1] = mad24(av, b.y, acc[i*4+1]);
        acc[i*4+2] = mad24(av, b.z, acc[i*4+2]);
        acc[i*4+3] = mad24(av, b.w, acc[i*4+3]);
      }
    }
    __syncthreads();
  }
  #pragma unroll
  for (int i = 0; i < 4; ++i) {
    #pragma unroll
    for (int j = 0; j < 4; ++j) {
      out[(size_t)(row0 + (ty<<2) + i) * DIMK + col0 + (tx<<2) + j] =
          (acc[i*4+j] + 32768) >> 16;
    }
  }
}

// ============================================================
extern "C" void kernel_launch(void* const* d_in, const int* in_sizes, int n_in,
                              void* d_out, int out_size, void* d_ws, size_t ws_size,
                              hipStream_t stream) {
  (void)in_sizes; (void)n_in; (void)out_size;
  const int*   x  = (const int*)d_in[0];
  const float* w1 = (const float*)d_in[1];
  const float* w2 = (const float*)d_in[2];
  const float* w3 = (const float*)d_in[3];
  int* out = (int*)d_out;
  char* ws = (char*)d_ws;

  if (ws_size >= WS_NEED) {
    char* t13 = ws + T13_OFF;
    int*  lut = (int*)(ws + LUT_OFF);
    int*  cs1 = (int*)(ws + CS1_OFF);
    int*  cs3 = (int*)(ws + CS3_OFF);
    char* xq  = ws + XQ_OFF;
    char* wq  = ws + WQ_OFF;

    hipMemsetAsync(ws + CS1_OFF, 0, 88064, stream);
    hipLaunchKernelGGL(lut_kernel, dim3(32), dim3(256), 0, stream, lut);
    hipLaunchKernelGGL(xq_kernel, dim3(1024), dim3(256), 0, stream, x, xq);
    hipLaunchKernelGGL(prequant_all, dim3(33024), dim3(256), 0, stream,
                       w1, w3, w2, wq, cs1, cs3);
    hipLaunchKernelGGL(up_gemm, dim3(688), dim3(512), 0, stream,
                       xq, wq, cs1, cs3, lut, t13);
    hipLaunchKernelGGL(down_gemm, dim3(256), dim3(512), 0, stream,
                       t13, wq + 4 * PLANE, wq + 5 * PLANE, out);
  } else {
    if (ws_size < (size_t)TOK * HID * sizeof(short)) return;
    short* t13 = (short*)ws;
    dim3 blk(16, 16);
    hipLaunchKernelGGL(ffn_up_f,   dim3(HID / BN, TOK / BT), blk, 0, stream, x, w1, w3, t13);
    hipLaunchKernelGGL(ffn_down_f, dim3(DIMK / BN, TOK / BT), blk, 0, stream, t13, w2, out);
  }
}

// Round 15
// 513.402 us; speedup vs baseline: 1.7052x; 1.7052x over previous
//
#include <hip/hip_runtime.h>
#include <hip/hip_fp16.h>
#include <math.h>

#define TOK  1024
#define DIMK 4096
#define HID  11008

typedef long long ll;
typedef int v4i  __attribute__((ext_vector_type(4)));
typedef int v16i __attribute__((ext_vector_type(16)));

// ---------- ws layout ----------
#define T13_OFF 0ull
#define LUT_OFF 11272192ull
#define CS1_OFF (LUT_OFF + 32768ull)
#define CS3_OFF (CS1_OFF + 44032ull)
#define XQ_OFF  (CS3_OFF + 44032ull)
#define WQ_OFF  (XQ_OFF + 4194304ull)
#define PLANE   45088768ull                          // 11008*4096 bytes
#define WS_NEED (WQ_OFF + 6ull * PLANE)              // ~273 MB

// ---------- exact fp16-silu requant (proven in round 2) ----------
__device__ __forceinline__ int gate_requant(int g) {
  const float vf = __half2float(__float2half((float)g * (1.0f / 65536.0f)));
  const float e32 = (float)exp(-(double)vf);
  const float e16 = __half2float(__float2half(e32));
  const float d16 = __half2float(__float2half(1.0f + e16));
  const float s16 = __half2float(__float2half(1.0f / d16));
  const float p16 = __half2float(__float2half(vf * s16));
  return __float2int_rn(p16 * 65536.0f);
}

__device__ __forceinline__ v16i vzero16() {
  v16i z;
  #pragma unroll
  for (int i = 0; i < 16; ++i) z[i] = 0;
  return z;
}

// async global->LDS, 16B per lane; lds ptr must be wave-uniform
__device__ __forceinline__ void gll(const void* g, void* l) {
  __builtin_amdgcn_global_load_lds((const __attribute__((address_space(1))) unsigned int*)g,
                                   (__attribute__((address_space(3))) unsigned int*)l,
                                   16, 0, 0);
}

// ============================================================
// Pre-pass kernels
// ============================================================

__global__ void lut_kernel(int* __restrict__ lut) {
  const int i = blockIdx.x * blockDim.x + threadIdx.x;   // 0..8191
  lut[i] = gate_requant(i - 4096);
}

// xq = (i8)(x - 128), packed bytes
__global__ __launch_bounds__(256)
void xq_kernel(const int* __restrict__ x, char* __restrict__ xq) {
  const size_t base = ((size_t)blockIdx.x * 256 + threadIdx.x) * 16;
  int w[4];
  #pragma unroll
  for (int i = 0; i < 4; ++i) {
    const int4 v = *reinterpret_cast<const int4*>(&x[base + i * 4]);
    w[i] = ((v.x & 255) | ((v.y & 255) << 8) | ((v.z & 255) << 16) | ((v.w & 255) << 24)) ^ 0x80808080;
  }
  *reinterpret_cast<int4*>(&xq[base]) = make_int4(w[0], w[1], w[2], w[3]);
}

// All three weight matrices in one dispatch (vectorized 16B stores).
__global__ __launch_bounds__(256)
void prequant_all(const float* __restrict__ w1, const float* __restrict__ w3,
                  const float* __restrict__ w2, char* __restrict__ wq,
                  int* __restrict__ cs1, int* __restrict__ cs3)
{
  const int bid = blockIdx.x;
  const int m = bid / 11008;            // 0,1,2 (uniform per block)
  const int rb = bid - m * 11008;
  const float* src = (m == 0) ? w1 : ((m == 1) ? w3 : w2);
  int4* lo = (int4*)(wq + (size_t)(2 * m) * PLANE);
  int4* hi = (int4*)(wq + (size_t)(2 * m + 1) * PLANE);
  const int t = threadIdx.x;
  const size_t fbase = (size_t)rb * 4096 + (size_t)t * 16;

  int sum = 0;
  int lob[4], hib[4];
  #pragma unroll
  for (int i = 0; i < 4; ++i) {
    const float4 f = *reinterpret_cast<const float4*>(&src[fbase + i * 4]);
    const int q0 = __float2int_rn(f.x * 65536.0f);
    const int q1 = __float2int_rn(f.y * 65536.0f);
    const int q2 = __float2int_rn(f.z * 65536.0f);
    const int q3 = __float2int_rn(f.w * 65536.0f);
    sum += q0 + q1 + q2 + q3;
    lob[i] = (q0 & 127) | ((q1 & 127) << 8) | ((q2 & 127) << 16) | ((q3 & 127) << 24);
    hib[i] = ((q0 >> 7) & 255) | (((q1 >> 7) & 255) << 8) |
             (((q2 >> 7) & 255) << 16) | (((q3 >> 7) & 255) << 24);
  }
  const size_t o = (size_t)rb * 256 + t;
  lo[o] = make_int4(lob[0], lob[1], lob[2], lob[3]);
  hi[o] = make_int4(hib[0], hib[1], hib[2], hib[3]);
  if (m < 2) {
    #pragma unroll
    for (int off = 32; off > 0; off >>= 1) sum += __shfl_xor(sum, off, 64);
    if ((t & 63) == 0) atomicAdd(((m == 0) ? cs1 : cs3) + rb, sum);
  }
}

// ============================================================
// Up GEMM (round-7 proven schedule, 252 us / MfmaUtil 32.5):
// BT=256, BN=64, 4 planes, BK=64; 512 thr = 8 waves. Per K-tile 2 phases:
//   {6 ds_read | 2 gll stage kt+2 -> s_barrier -> lgkmcnt(0)+sched_barrier
//    -> setprio(1) 8xMFMA setprio(0) -> s_barrier}
// vmcnt counted once per tile. Triple buffer 3x32KB. XCD swizzle 688=8*86.
// ============================================================
#define UP_BUF 32768

__global__ __launch_bounds__(512, 1)
void up_gemm(const char* __restrict__ xq, const char* __restrict__ wq,
             const int* __restrict__ csum1, const int* __restrict__ csum3,
             const int* __restrict__ lut, char* __restrict__ t13)
{
  __shared__ char smem[3 * UP_BUF];
  const int tid = threadIdx.x;
  const int w = tid >> 6, l = tid & 63;
  const int rf = w & 3, cf = w >> 2;
  const int l16 = l * 16;

  // bijective XCD swizzle: 688 = 8 * 86
  const int flat = blockIdx.x;
  const int g = (flat & 7) * 86 + (flat >> 3);
  const int col0 = (g >> 2) * 64;
  const int row0 = (g & 3) * 256;

  const char* gA = xq + (size_t)(row0 + w * 32 + (l & 31)) * DIMK + (l >> 5) * 16;
  const char* gB = wq + (size_t)(w >> 1) * PLANE
                 + (size_t)(col0 + (w & 1) * 32 + (l & 31)) * DIMK + (l >> 5) * 16;
  const unsigned dA0 = (2 * w + 0) * 1024, dA1 = (2 * w + 1) * 1024;
  const unsigned dB0 = 16384 + (2 * w + 0) * 1024, dB1 = 16384 + (2 * w + 1) * 1024;

  v16i acc[2][4];
  #pragma unroll
  for (int m = 0; m < 2; ++m)
    #pragma unroll
    for (int p = 0; p < 4; ++p) acc[m][p] = vzero16();

  // prologue: stage tiles 0 and 1; wait tile 0
  gll(gA, smem + dA0);       gll(gA + 32, smem + dA1);
  gll(gB, smem + dB0);       gll(gB + 32, smem + dB1);
  gll(gA + 64, smem + UP_BUF + dA0);  gll(gA + 96, smem + UP_BUF + dA1);
  gll(gB + 64, smem + UP_BUF + dB0);  gll(gB + 96, smem + UP_BUF + dB1);
  asm volatile("s_waitcnt vmcnt(4)" ::: "memory");
  __builtin_amdgcn_s_barrier();

  const int NT = DIMK / 64;
  unsigned co = 0, so = 2 * UP_BUF;
  for (int kt = 0; kt < NT; ++kt) {
    const char* sb = smem + co;
    const bool st = (kt + 2 < NT);
    const int kb = (kt + 2) * 64;
    // ---------------- phase 0 (ks = 0) ----------------
    {
      const v4i av0 = *(const v4i*)(sb + (rf * 4 + 0) * 1024 + l16);
      const v4i av1 = *(const v4i*)(sb + (rf * 4 + 2) * 1024 + l16);
      const v4i b0  = *(const v4i*)(sb + 16384 + (0 * 4 + cf * 2) * 1024 + l16);
      const v4i b1  = *(const v4i*)(sb + 16384 + (1 * 4 + cf * 2) * 1024 + l16);
      const v4i b2  = *(const v4i*)(sb + 16384 + (2 * 4 + cf * 2) * 1024 + l16);
      const v4i b3  = *(const v4i*)(sb + 16384 + (3 * 4 + cf * 2) * 1024 + l16);
      if (st) { gll(gA + kb, smem + so + dA0); gll(gA + kb + 32, smem + so + dA1); }
      __builtin_amdgcn_s_barrier();
      asm volatile("s_waitcnt lgkmcnt(0)" ::: "memory");
      __builtin_amdgcn_sched_barrier(0);
      __builtin_amdgcn_s_setprio(1);
      acc[0][0] = __builtin_amdgcn_mfma_i32_32x32x32_i8(av0, b0, acc[0][0], 0, 0, 0);
      acc[0][1] = __builtin_amdgcn_mfma_i32_32x32x32_i8(av0, b1, acc[0][1], 0, 0, 0);
      acc[0][2] = __builtin_amdgcn_mfma_i32_32x32x32_i8(av0, b2, acc[0][2], 0, 0, 0);
      acc[0][3] = __builtin_amdgcn_mfma_i32_32x32x32_i8(av0, b3, acc[0][3], 0, 0, 0);
      acc[1][0] = __builtin_amdgcn_mfma_i32_32x32x32_i8(av1, b0, acc[1][0], 0, 0, 0);
      acc[1][1] = __builtin_amdgcn_mfma_i32_32x32x32_i8(av1, b1, acc[1][1], 0, 0, 0);
      acc[1][2] = __builtin_amdgcn_mfma_i32_32x32x32_i8(av1, b2, acc[1][2], 0, 0, 0);
      acc[1][3] = __builtin_amdgcn_mfma_i32_32x32x32_i8(av1, b3, acc[1][3], 0, 0, 0);
      __builtin_amdgcn_s_setprio(0);
      __builtin_amdgcn_s_barrier();
    }
    // ---------------- phase 1 (ks = 1) ----------------
    {
      const v4i av0 = *(const v4i*)(sb + (rf * 4 + 1) * 1024 + l16);
      const v4i av1 = *(const v4i*)(sb + (rf * 4 + 3) * 1024 + l16);
      const v4i b0  = *(const v4i*)(sb + 16384 + (0 * 4 + cf * 2 + 1) * 1024 + l16);
      const v4i b1  = *(const v4i*)(sb + 16384 + (1 * 4 + cf * 2 + 1) * 1024 + l16);
      const v4i b2  = *(const v4i*)(sb + 16384 + (2 * 4 + cf * 2 + 1) * 1024 + l16);
      const v4i b3  = *(const v4i*)(sb + 16384 + (3 * 4 + cf * 2 + 1) * 1024 + l16);
      if (st) { gll(gB + kb, smem + so + dB0); gll(gB + kb + 32, smem + so + dB1); }
      __builtin_amdgcn_s_barrier();
      asm volatile("s_waitcnt lgkmcnt(0)" ::: "memory");
      __builtin_amdgcn_sched_barrier(0);
      __builtin_amdgcn_s_setprio(1);
      acc[0][0] = __builtin_amdgcn_mfma_i32_32x32x32_i8(av0, b0, acc[0][0], 0, 0, 0);
      acc[0][1] = __builtin_amdgcn_mfma_i32_32x32x32_i8(av0, b1, acc[0][1], 0, 0, 0);
      acc[0][2] = __builtin_amdgcn_mfma_i32_32x32x32_i8(av0, b2, acc[0][2], 0, 0, 0);
      acc[0][3] = __builtin_amdgcn_mfma_i32_32x32x32_i8(av0, b3, acc[0][3], 0, 0, 0);
      acc[1][0] = __builtin_amdgcn_mfma_i32_32x32x32_i8(av1, b0, acc[1][0], 0, 0, 0);
      acc[1][1] = __builtin_amdgcn_mfma_i32_32x32x32_i8(av1, b1, acc[1][1], 0, 0, 0);
      acc[1][2] = __builtin_amdgcn_mfma_i32_32x32x32_i8(av1, b2, acc[1][2], 0, 0, 0);
      acc[1][3] = __builtin_amdgcn_mfma_i32_32x32x32_i8(av1, b3, acc[1][3], 0, 0, 0);
      __builtin_amdgcn_s_setprio(0);
      if (st) { asm volatile("s_waitcnt vmcnt(4)" ::: "memory"); }
      else    { asm volatile("s_waitcnt vmcnt(0)" ::: "memory"); }
      __builtin_amdgcn_s_barrier();
    }
    if (st) so = (so == 2 * UP_BUF) ? 0 : so + UP_BUF;
    co = (co == 2 * UP_BUF) ? 0 : co + UP_BUF;
  }

  const int col = col0 + cf * 32 + (l & 31);
  const int cs1v = csum1[col], cs3v = csum3[col];
  #pragma unroll
  for (int m = 0; m < 2; ++m) {
    #pragma unroll
    for (int r = 0; r < 16; ++r) {
      const int row = row0 + rf * 64 + m * 32 + (r & 3) + 8 * (r >> 2) + 4 * (l >> 5);
      const ll t1 = (ll)acc[m][0][r] + (((ll)acc[m][1][r] + cs1v) << 7);
      int gg = (int)((t1 + 32768) >> 16);
      gg = gg < -4096 ? -4096 : (gg > 4095 ? 4095 : gg);
      const ll t3 = (ll)acc[m][2][r] + (((ll)acc[m][3][r] + cs3v) << 7);
      const int q3 = (int)((t3 + 32768) >> 16);
      const int gate = lut[gg + 4096];
      t13[(size_t)row * HID + col] = (char)((int)(((ll)gate * q3 + 32768) >> 16));
    }
  }
}

// ============================================================
// Down GEMM (round-7 proven): BT=256, BN=64, 2 planes, BK=64 over HID;
// 512 thr = 8 waves, triple buffer 3x24KB, grid 256 = 1/CU.
// ============================================================
#define DN_BUF 24576

__global__ __launch_bounds__(512, 1)
void down_gemm(const char* __restrict__ t13, const char* __restrict__ w2lo,
               const char* __restrict__ w2hi, int* __restrict__ out)
{
  __shared__ char smem[3 * DN_BUF];
  const int tid = threadIdx.x;
  const int w = tid >> 6, l = tid & 63;
  const int rf = w & 3, cf = w >> 2;
  const int l16 = l * 16;

  // bijective XCD swizzle: 256 = 8 * 32
  const int flat = blockIdx.x;
  const int g = (flat & 7) * 32 + (flat >> 3);
  const int col0 = (g >> 2) * 64;
  const int row0 = (g & 3) * 256;

  const char* gA = t13 + (size_t)(row0 + w * 32 + (l & 31)) * HID + (l >> 5) * 16;
  const char* pB = (w >> 2) ? w2hi : w2lo;
  const char* gB = pB + (size_t)(col0 + ((w >> 1) & 1) * 32 + (l & 31)) * HID
                 + (w & 1) * 32 + (l >> 5) * 16;
  const unsigned dA0 = (2 * w + 0) * 1024, dA1 = (2 * w + 1) * 1024;
  const unsigned dB = 16384 + w * 1024;

  v16i acc[2][2];
  #pragma unroll
  for (int m = 0; m < 2; ++m)
    #pragma unroll
    for (int p = 0; p < 2; ++p) acc[m][p] = vzero16();

  // prologue: tiles 0,1 (3 gll each); wait tile 0
  gll(gA, smem + dA0);  gll(gA + 32, smem + dA1);  gll(gB, smem + dB);
  gll(gA + 64, smem + DN_BUF + dA0);  gll(gA + 96, smem + DN_BUF + dA1);
  gll(gB + 64, smem + DN_BUF + dB);
  asm volatile("s_waitcnt vmcnt(3)" ::: "memory");
  __builtin_amdgcn_s_barrier();

  const int NT = HID / 64;   // 172
  unsigned co = 0, so = 2 * DN_BUF;
  for (int kt = 0; kt < NT; ++kt) {
    const char* sb = smem + co;
    const bool st = (kt + 2 < NT);
    const int kb = (kt + 2) * 64;
    // ---------------- phase 0 (ks = 0) ----------------
    {
      const v4i av0 = *(const v4i*)(sb + (rf * 4 + 0) * 1024 + l16);
      const v4i av1 = *(const v4i*)(sb + (rf * 4 + 2) * 1024 + l16);
      const v4i bL  = *(const v4i*)(sb + 16384 + (0 * 4 + cf * 2) * 1024 + l16);
      const v4i bH  = *(const v4i*)(sb + 16384 + (1 * 4 + cf * 2) * 1024 + l16);
      if (st) { gll(gA + kb, smem + so + dA0); gll(gA + kb + 32, smem + so + dA1); }
      __builtin_amdgcn_s_barrier();
      asm volatile("s_waitcnt lgkmcnt(0)" ::: "memory");
      __builtin_amdgcn_sched_barrier(0);
      __builtin_amdgcn_s_setprio(1);
      acc[0][0] = __builtin_amdgcn_mfma_i32_32x32x32_i8(av0, bL, acc[0][0], 0, 0, 0);
      acc[0][1] = __builtin_amdgcn_mfma_i32_32x32x32_i8(av0, bH, acc[0][1], 0, 0, 0);
      acc[1][0] = __builtin_amdgcn_mfma_i32_32x32x32_i8(av1, bL, acc[1][0], 0, 0, 0);
      acc[1][1] = __builtin_amdgcn_mfma_i32_32x32x32_i8(av1, bH, acc[1][1], 0, 0, 0);
      __builtin_amdgcn_s_setprio(0);
      __builtin_amdgcn_s_barrier();
    }
    // ---------------- phase 1 (ks = 1) ----------------
    {
      const v4i av0 = *(const v4i*)(sb + (rf * 4 + 1) * 1024 + l16);
      const v4i av1 = *(const v4i*)(sb + (rf * 4 + 3) * 1024 + l16);
      const v4i bL  = *(const v4i*)(sb + 16384 + (0 * 4 + cf * 2 + 1) * 1024 + l16);
      const v4i bH  = *(const v4i*)(sb + 16384 + (1 * 4 + cf * 2 + 1) * 1024 + l16);
      if (st) { gll(gB + kb, smem + so + dB); }
      __builtin_amdgcn_s_barrier();
      asm volatile("s_waitcnt lgkmcnt(0)" ::: "memory");
      __builtin_amdgcn_sched_barrier(0);
      __builtin_amdgcn_s_setprio(1);
      acc[0][0] = __builtin_amdgcn_mfma_i32_32x32x32_i8(av0, bL, acc[0][0], 0, 0, 0);
      acc[0][1] = __builtin_amdgcn_mfma_i32_32x32x32_i8(av0, bH, acc[0][1], 0, 0, 0);
      acc[1][0] = __builtin_amdgcn_mfma_i32_32x32x32_i8(av1, bL, acc[1][0], 0, 0, 0);
      acc[1][1] = __builtin_amdgcn_mfma_i32_32x32x32_i8(av1, bH, acc[1][1], 0, 0, 0);
      __builtin_amdgcn_s_setprio(0);
      if (st) { asm volatile("s_waitcnt vmcnt(3)" ::: "memory"); }
      else    { asm volatile("s_waitcnt vmcnt(0)" ::: "memory"); }
      __builtin_amdgcn_s_barrier();
    }
    if (st) so = (so == 2 * DN_BUF) ? 0 : so + DN_BUF;
    co = (co == 2 * DN_BUF) ? 0 : co + DN_BUF;
  }

  const int col = col0 + cf * 32 + (l & 31);
  #pragma unroll
  for (int m = 0; m < 2; ++m) {
    #pragma unroll
    for (int r = 0; r < 16; ++r) {
      const int row = row0 + rf * 64 + m * 32 + (r & 3) + 8 * (r >> 2) + 4 * (l >> 5);
      out[(size_t)row * DIMK + col] =
          (int)((((ll)acc[m][0][r] + ((ll)acc[m][1][r] << 7)) + 32768) >> 16);
    }
  }
}

// ============================================================
// Fallback (round-2 passing VALU kernels, used if ws too small)
// ============================================================
#define BT 64
#define BN 64
#define BK 64
#define LDST 68

__device__ __forceinline__ int mad24(int a, int b, int c) {
  return ((a << 8) >> 8) * ((b << 8) >> 8) + c;
}

__global__ __launch_bounds__(256)
void ffn_up_f(const int* __restrict__ x, const float* __restrict__ w1,
              const float* __restrict__ w3, short* __restrict__ t13)
{
  __shared__ int As[BT][LDST];
  __shared__ int B1[BK][LDST];
  __shared__ int B3[BK][LDST];
  const int tx = threadIdx.x, ty = threadIdx.y;
  const int tid = ty * 16 + tx;
  const int col0 = blockIdx.x * BN;
  const int row0 = blockIdx.y * BT;
  const int lr = tid >> 4;
  const int lk = (tid & 15) << 2;
  int acc1[16] = {0};
  int acc3[16] = {0};
  for (int k0 = 0; k0 < DIMK; k0 += BK) {
    #pragma unroll
    for (int m = 0; m < 4; ++m) {
      const int r = lr + m * 16;
      *reinterpret_cast<int4*>(&As[r][lk]) =
          *reinterpret_cast<const int4*>(&x[(size_t)(row0 + r) * DIMK + k0 + lk]);
      const float4 f1 = *reinterpret_cast<const float4*>(&w1[(size_t)(col0 + r) * DIMK + k0 + lk]);
      const float4 f3 = *reinterpret_cast<const float4*>(&w3[(size_t)(col0 + r) * DIMK + k0 + lk]);
      B1[lk + 0][r] = __float2int_rn(f1.x * 65536.0f);
      B1[lk + 1][r] = __float2int_rn(f1.y * 65536.0f);
      B1[lk + 2][r] = __float2int_rn(f1.z * 65536.0f);
      B1[lk + 3][r] = __float2int_rn(f1.w * 65536.0f);
      B3[lk + 0][r] = __float2int_rn(f3.x * 65536.0f);
      B3[lk + 1][r] = __float2int_rn(f3.y * 65536.0f);
      B3[lk + 2][r] = __float2int_rn(f3.z * 65536.0f);
      B3[lk + 3][r] = __float2int_rn(f3.w * 65536.0f);
    }
    __syncthreads();
    #pragma unroll 8
    for (int kk = 0; kk < BK; ++kk) {
      const int4 b1 = *reinterpret_cast<const int4*>(&B1[kk][tx << 2]);
      const int4 b3 = *reinterpret_cast<const int4*>(&B3[kk][tx << 2]);
      #pragma unroll
      for (int i = 0; i < 4; ++i) {
        const int av = As[(ty << 2) + i][kk] & 255;
        acc1[i*4+0] = mad24(av, b1.x, acc1[i*4+0]);
        acc1[i*4+1] = mad24(av, b1.y, acc1[i*4+1]);
        acc1[i*4+2] = mad24(av, b1.z, acc1[i*4+2]);
        acc1[i*4+3] = mad24(av, b1.w, acc1[i*4+3]);
        acc3[i*4+0] = mad24(av, b3.x, acc3[i*4+0]);
        acc3[i*4+1] = mad24(av, b3.y, acc3[i*4+1]);
        acc3[i*4+2] = mad24(av, b3.z, acc3[i*4+2]);
        acc3[i*4+3] = mad24(av, b3.w, acc3[i*4+3]);
      }
    }
    __syncthreads();
  }
  #pragma unroll
  for (int i = 0; i < 4; ++i) {
    #pragma unroll
    for (int j = 0; j < 4; ++j) {
      const int g    = (acc1[i*4+j] + 32768) >> 16;
      const int q3   = (acc3[i*4+j] + 32768) >> 16;
      const int gate = gate_requant(g);
      const int tv = (int)(((ll)gate * (ll)q3 + 32768) >> 16);
      t13[(size_t)(row0 + (ty<<2) + i) * HID + col0 + (tx<<2) + j] = (short)tv;
    }
  }
}

__global__ __launch_bounds__(256)
void ffn_down_f(const short* __restrict__ t13, const float* __restrict__ w2,
                int* __restrict__ out)
{
  __shared__ int As[BT][LDST];
  __shared__ int Bs[BK][LDST];
  const int tx = threadIdx.x, ty = threadIdx.y;
  const int tid = ty * 16 + tx;
  const int col0 = blockIdx.x * BN;
  const int row0 = blockIdx.y * BT;
  const int lr = tid >> 4;
  const int lk = (tid & 15) << 2;
  const int ar = tid >> 3;
  const int ak = (tid & 7) << 3;
  int acc[16] = {0};
  for (int k0 = 0; k0 < HID; k0 += BK) {
    #pragma unroll
    for (int m = 0; m < 2; ++m) {
      const int r = ar + m * 32;
      const int4 v = *reinterpret_cast<const int4*>(&t13[(size_t)(row0 + r) * HID + k0 + ak]);
      As[r][ak+0] = (v.x << 16) >> 16;  As[r][ak+1] = v.x >> 16;
      As[r][ak+2] = (v.y << 16) >> 16;  As[r][ak+3] = v.y >> 16;
      As[r][ak+4] = (v.z << 16) >> 16;  As[r][ak+5] = v.z >> 16;
      As[r][ak+6] = (v.w << 16) >> 16;  As[r][ak+7] = v.w >> 16;
    }
    #pragma unroll
    for (int m = 0; m < 4; ++m) {
      const int r = lr + m * 16;
      const float4 f = *reinterpret_cast<const float4*>(&w2[(size_t)(col0 + r) * HID + k0 + lk]);
      Bs[lk + 0][r] = __float2int_rn(f.x * 65536.0f);
      Bs[lk + 1][r] = __float2int_rn(f.y * 65536.0f);
      Bs[lk + 2][r] = __float2int_rn(f.z * 65536.0f);
      Bs[lk + 3][r] = __float2int_rn(f.w * 65536.0f);
    }
    __syncthreads();
    #pragma unroll 8
    for (int kk = 0; kk < BK; ++kk) {
      const int4 b = *reinterpret_cast<const int4*>(&Bs[kk][tx << 2]);
      #pragma unroll
      for (int i = 0; i < 4; ++i) {
        const int av = As[(ty << 2) + i][kk];
        acc[i*4+0] = mad24(av, b.x, acc[i*4+0]);
        acc[i*4+1] = mad24(av, b.y, acc[i*4+1]);
        acc[i*4+2] = mad24(av, b.z, acc[i*4+2]);
        acc[i*4+3] = mad24(av, b.w, acc[i*4+3]);
      }
    }
    __syncthreads();
  }
  #pragma unroll
  for (int i = 0; i < 4; ++i) {
    #pragma unroll
    for (int j = 0; j < 4; ++j) {
      out[(size_t)(row0 + (ty<<2) + i) * DIMK + col0 + (tx<<2) + j] =
          (acc[i*4+j] + 32768) >> 16;
    }
  }
}

// ============================================================
extern "C" void kernel_launch(void* const* d_in, const int* in_sizes, int n_in,
                              void* d_out, int out_size, void* d_ws, size_t ws_size,
                              hipStream_t stream) {
  (void)in_sizes; (void)n_in; (void)out_size;
  const int*   x  = (const int*)d_in[0];
  const float* w1 = (const float*)d_in[1];
  const float* w2 = (const float*)d_in[2];
  const float* w3 = (const float*)d_in[3];
  int* out = (int*)d_out;
  char* ws = (char*)d_ws;

  if (ws_size >= WS_NEED) {
    char* t13 = ws + T13_OFF;
    int*  lut = (int*)(ws + LUT_OFF);
    int*  cs1 = (int*)(ws + CS1_OFF);
    int*  cs3 = (int*)(ws + CS3_OFF);
    char* xq  = ws + XQ_OFF;
    char* wq  = ws + WQ_OFF;

    hipMemsetAsync(ws + CS1_OFF, 0, 88064, stream);
    hipLaunchKernelGGL(lut_kernel, dim3(32), dim3(256), 0, stream, lut);
    hipLaunchKernelGGL(xq_kernel, dim3(1024), dim3(256), 0, stream, x, xq);
    hipLaunchKernelGGL(prequant_all, dim3(33024), dim3(256), 0, stream,
                       w1, w3, w2, wq, cs1, cs3);
    hipLaunchKernelGGL(up_gemm, dim3(688), dim3(512), 0, stream,
                       xq, wq, cs1, cs3, lut, t13);
    hipLaunchKernelGGL(down_gemm, dim3(256), dim3(512), 0, stream,
                       t13, wq + 4 * PLANE, wq + 5 * PLANE, out);
  } else {
    if (ws_size < (size_t)TOK * HID * sizeof(short)) return;
    short* t13 = (short*)ws;
    dim3 blk(16, 16);
    hipLaunchKernelGGL(ffn_up_f,   dim3(HID / BN, TOK / BT), blk, 0, stream, x, w1, w3, t13);
    hipLaunchKernelGGL(ffn_down_f, dim3(DIMK / BN, TOK / BT), blk, 0, stream, t13, w2, out);
  }
}